// Round 13
// baseline (313.800 us; speedup 1.0000x reference)
//
#include <hip/hip_runtime.h>

// ---------------------------------------------------------------------------
// ROIAwareGCN: 3x GCNConv + mean-pool + MLP.
// R1: atomic pool -> segmented reduction. R2: split-bf16 MFMA GEMM, bf16 t.
// R3: padded CSR. R4: pool+mlp fused. R5/R6: single-block scan.
// R7: bucket atomics REGRESSED. R8: LDS sort CRASHED. R9: col-only NEUTRAL.
// R10: wgt[] eliminated (dinv in GEMM epilogue; pad cols -> zero row n).
// R11: scan split into k_sum/k_out across 13 CUs (44.5us serial node gone).
// R12: rows padded to 16 (was 4): typical deg~12 row previously ran the
//      8-burst + 4-tail SERIALLY (16-burst never engaged). Now every row is
//      exactly k x 16 slots -> single 16-deep gather burst, no tails. Pad
//      slots gather the L1-resident zero row (free). col = E+15n worst case.
// ---------------------------------------------------------------------------

typedef __bf16 bf16x8 __attribute__((ext_vector_type(8)));
typedef float f32x4 __attribute__((ext_vector_type(4)));

__device__ __forceinline__ float bflo(unsigned u) { return __uint_as_float(u << 16); }
__device__ __forceinline__ float bfhi(unsigned u) { return __uint_as_float(u & 0xffff0000u); }

union BF2 {
    __bf16 h[2];
    unsigned u;
};

// ---------------- W pre-pack into MFMA B-fragment layout ----------------
__device__ __forceinline__ void wpack_block(const float* __restrict__ W,
                                            __bf16* __restrict__ hi,
                                            __bf16* __restrict__ lo, int N, int b, int l) {
    int t = b >> 2, c = b & 3;
    int k0 = c * 32 + (l >> 4) * 8;
    int ncol = t * 16 + (l & 15);
    size_t base = ((size_t)b * 64 + l) * 8;
#pragma unroll
    for (int j = 0; j < 8; j++) {
        float v = W[(size_t)(k0 + j) * N + ncol];
        __bf16 h = (__bf16)v;
        hi[base + j] = h;
        lo[base + j] = (__bf16)(v - (float)h);
    }
}

// ---- fused: degree count + graph boundaries + wpack(W1,W2,W3) ----
__global__ void k_pre(const int* __restrict__ dst, int* __restrict__ cnt,
                      const int* __restrict__ batch, int* __restrict__ gstart,
                      const float* __restrict__ W1, __bf16* __restrict__ Wp1h,
                      __bf16* __restrict__ Wp1l,
                      const float* __restrict__ W2, const float* __restrict__ W3,
                      __bf16* __restrict__ Wp2h, __bf16* __restrict__ Wp2l,
                      __bf16* __restrict__ Wp3h, __bf16* __restrict__ Wp3l,
                      int E, int n, int G, int EB) {
    int b = blockIdx.x;
    if (b < EB) {
        int e = b * 256 + threadIdx.x;
        if (e < E) atomicAdd(&cnt[dst[e]], 1);
    } else if (b == EB) {
        int g = threadIdx.x;
        if (g <= G) {
            int lo = 0, hi = n;
            while (lo < hi) {
                int mid = (lo + hi) >> 1;
                if (batch[mid] < g) lo = mid + 1; else hi = mid;
            }
            gstart[g] = lo;  // lower_bound: first i with batch[i] >= g
        }
    } else {
        int b64 = (b - EB - 1) * 4 + (threadIdx.x >> 6);  // 0..79
        int l = threadIdx.x & 63;
        if (b64 < 32) wpack_block(W1, Wp1h, Wp1l, 128, b64, l);
        else if (b64 < 64) wpack_block(W2, Wp2h, Wp2l, 128, b64 - 32, l);
        else if (b64 < 80) wpack_block(W3, Wp3h, Wp3l, 64, b64 - 64, l);
    }
}

#define PAD(c) (((c) + 15) & ~15)

// ---------------- scan stage 1: per-chunk padded sums + dinv ----------------
__global__ __launch_bounds__(1024) void k_sum(const int* __restrict__ cnt,
                                              int* __restrict__ partial,
                                              float* __restrict__ dinv,
                                              unsigned int* __restrict__ tz128,
                                              unsigned int* __restrict__ tz64, int n) {
    __shared__ int ws[16];
    int b = blockIdx.x;
    int tid = threadIdx.x;
    int lane = tid & 63;
    int wid = tid >> 6;
    if (b == 0) {  // zero row n of the two gather targets (64 + 32 uints)
        if (tid < 64) tz128[(size_t)n * 64 + tid] = 0u;
        else if (tid < 96) tz64[(size_t)n * 32 + (tid - 64)] = 0u;
    }
    int i0 = (b << 12) + tid * 4;
    int s = 0;
    if (i0 + 3 < n) {
        int4 v = *(const int4*)(cnt + i0);
        float4 dv;
        dv.x = rsqrtf((float)(v.x + 1));
        dv.y = rsqrtf((float)(v.y + 1));
        dv.z = rsqrtf((float)(v.z + 1));
        dv.w = rsqrtf((float)(v.w + 1));
        *(float4*)(dinv + i0) = dv;
        s = PAD(v.x) + PAD(v.y) + PAD(v.z) + PAD(v.w);
    } else if (i0 < n) {
#pragma unroll
        for (int j = 0; j < 4; j++) {
            if (i0 + j < n) {
                int v = cnt[i0 + j];
                dinv[i0 + j] = rsqrtf((float)(v + 1));
                s += PAD(v);
            }
        }
    }
#pragma unroll
    for (int d = 32; d > 0; d >>= 1) s += __shfl_xor(s, d);
    if (lane == 0) ws[wid] = s;
    __syncthreads();
    if (tid == 0) {
        int t = 0;
#pragma unroll
        for (int k = 0; k < 16; k++) t += ws[k];
        partial[b] = t;
    }
}

// ---------------- scan stage 2: in-block scan + outputs ----------------
__global__ __launch_bounds__(1024) void k_out(const int* __restrict__ cnt,
                                              const int* __restrict__ partial,
                                              int* __restrict__ rowptr,
                                              int* __restrict__ fill2,
                                              int* __restrict__ col,
                                              int n, int nchunks) {
    __shared__ int lsum[16];
    __shared__ int base_s;
    int b = blockIdx.x;
    int tid = threadIdx.x;
    int lane = tid & 63;
    int wid = tid >> 6;
    if (tid == 0) {
        int acc = 0;
        for (int c = 0; c < b; c++) acc += partial[c];
        base_s = acc;
    }
    if (b == 0 && tid == 1) {  // total -> rowptr[n]
        int acc = 0;
        for (int c = 0; c < nchunks; c++) acc += partial[c];
        rowptr[n] = acc;
    }
    int i0 = (b << 12) + tid * 4;
    int v[4], pv[4];
    int s = 0;
    if (i0 < n) {
        if (i0 + 3 < n) {
            int4 vv = *(const int4*)(cnt + i0);
            v[0] = vv.x; v[1] = vv.y; v[2] = vv.z; v[3] = vv.w;
        } else {
#pragma unroll
            for (int j = 0; j < 4; j++) v[j] = (i0 + j < n) ? cnt[i0 + j] : 0;
        }
    } else {
#pragma unroll
        for (int j = 0; j < 4; j++) v[j] = 0;
    }
#pragma unroll
    for (int j = 0; j < 4; j++) {
        pv[j] = PAD(v[j]);
        s += pv[j];
    }
    int sc = s;
#pragma unroll
    for (int d = 1; d < 64; d <<= 1) {
        int o = __shfl_up(sc, d);
        if (lane >= d) sc += o;
    }
    int exc = sc - s;
    if (lane == 63) lsum[wid] = sc;
    __syncthreads();
    if (wid == 0) {
        int val = (lane < 16) ? lsum[lane] : 0;
        int sc2 = val;
#pragma unroll
        for (int d = 1; d < 16; d <<= 1) {
            int o = __shfl_up(sc2, d);
            if (lane >= d) sc2 += o;
        }
        if (lane < 16) lsum[lane] = sc2 - val;
    }
    __syncthreads();
    if (i0 >= n) return;
    int off = base_s + lsum[wid] + exc;
    int o0 = off;
    int o1 = o0 + pv[0];
    int o2 = o1 + pv[1];
    int o3 = o2 + pv[2];
    int o4 = o3 + pv[3];
    if (i0 + 3 < n) {
        int4 ov = {o0, o1, o2, o3};
        *(int4*)(rowptr + i0) = ov;
        *(int4*)(fill2 + i0) = ov;
    } else {
        int oo[4] = {o0, o1, o2, o3};
#pragma unroll
        for (int j = 0; j < 4; j++) {
            if (i0 + j < n) {
                rowptr[i0 + j] = oo[j];
                fill2[i0 + j] = oo[j];
            }
        }
    }
    for (int p = o0 + v[0]; p < o1; p++) col[p] = n;
    if (i0 + 1 < n) for (int p = o1 + v[1]; p < o2; p++) col[p] = n;
    if (i0 + 2 < n) for (int p = o2 + v[2]; p < o3; p++) col[p] = n;
    if (i0 + 3 < n) for (int p = o3 + v[3]; p < o4; p++) col[p] = n;
}

// ---------------- CSR scatter: col only ----------------
__global__ void k_csr(const int* __restrict__ src, const int* __restrict__ dst,
                      int* __restrict__ fill2, int* __restrict__ col, int E) {
    int e = blockIdx.x * blockDim.x + threadIdx.x;
    if (e >= E) return;
    int pos = atomicAdd(&fill2[dst[e]], 1);
    col[pos] = src[e];
}

// ---------------- MFMA GEMMs (epilogue scales row by dinv) ----------------
template <int NT>
__global__ __launch_bounds__(256) void k_gemm_f32(const float* __restrict__ A,
                                                  const __bf16* __restrict__ Wp_hi,
                                                  const __bf16* __restrict__ Wp_lo,
                                                  const float* __restrict__ dinv,
                                                  __bf16* __restrict__ Cbf, int n) {
    constexpr int N = NT * 16;
    int wave = (int)((blockIdx.x * 256u + threadIdx.x) >> 6);
    int lane = threadIdx.x & 63;
    int row0 = wave * 16;
    if (row0 >= n) return;
    int m = lane & 15;
    int q = lane >> 4;
    int row = row0 + m;
    if (row >= n) row = n - 1;
    const float* ap = A + (size_t)row * 128 + q * 8;
    bf16x8 ahi[4], alo[4];
#pragma unroll
    for (int c = 0; c < 4; c++) {
        float4 v0 = *(const float4*)(ap + c * 32);
        float4 v1 = *(const float4*)(ap + c * 32 + 4);
        float vv[8] = {v0.x, v0.y, v0.z, v0.w, v1.x, v1.y, v1.z, v1.w};
#pragma unroll
        for (int j = 0; j < 8; j++) {
            __bf16 h = (__bf16)vv[j];
            ahi[c][j] = h;
            alo[c][j] = (__bf16)(vv[j] - (float)h);
        }
    }
    float dscale[4];
#pragma unroll
    for (int r = 0; r < 4; r++) {
        int rr = row0 + q * 4 + r;
        dscale[r] = dinv[rr < n ? rr : (n - 1)];
    }
#pragma unroll
    for (int t = 0; t < NT; t++) {
        f32x4 acc = {0.f, 0.f, 0.f, 0.f};
#pragma unroll
        for (int c = 0; c < 4; c++) {
            size_t off = ((size_t)(t * 4 + c) * 64 + lane) * 8;
            bf16x8 bh = *(const bf16x8*)(Wp_hi + off);
            bf16x8 bl = *(const bf16x8*)(Wp_lo + off);
            acc = __builtin_amdgcn_mfma_f32_16x16x32_bf16(ahi[c], bh, acc, 0, 0, 0);
            acc = __builtin_amdgcn_mfma_f32_16x16x32_bf16(alo[c], bh, acc, 0, 0, 0);
            acc = __builtin_amdgcn_mfma_f32_16x16x32_bf16(ahi[c], bl, acc, 0, 0, 0);
        }
        int colx = t * 16 + m;
#pragma unroll
        for (int r = 0; r < 4; r++) {
            int orow = row0 + q * 4 + r;
            if (orow < n) Cbf[(size_t)orow * N + colx] = (__bf16)(acc[r] * dscale[r]);
        }
    }
}

template <int NT>
__global__ __launch_bounds__(256) void k_gemm_bf16(const __bf16* __restrict__ A,
                                                   const __bf16* __restrict__ Wp_hi,
                                                   const __bf16* __restrict__ Wp_lo,
                                                   const float* __restrict__ dinv,
                                                   __bf16* __restrict__ Cbf, int n) {
    constexpr int N = NT * 16;
    int wave = (int)((blockIdx.x * 256u + threadIdx.x) >> 6);
    int lane = threadIdx.x & 63;
    int row0 = wave * 16;
    if (row0 >= n) return;
    int m = lane & 15;
    int q = lane >> 4;
    int row = row0 + m;
    if (row >= n) row = n - 1;
    const __bf16* ap = A + (size_t)row * 128 + q * 8;
    bf16x8 a[4];
#pragma unroll
    for (int c = 0; c < 4; c++) a[c] = *(const bf16x8*)(ap + c * 32);
    float dscale[4];
#pragma unroll
    for (int r = 0; r < 4; r++) {
        int rr = row0 + q * 4 + r;
        dscale[r] = dinv[rr < n ? rr : (n - 1)];
    }
#pragma unroll
    for (int t = 0; t < NT; t++) {
        f32x4 acc = {0.f, 0.f, 0.f, 0.f};
#pragma unroll
        for (int c = 0; c < 4; c++) {
            size_t off = ((size_t)(t * 4 + c) * 64 + lane) * 8;
            bf16x8 bh = *(const bf16x8*)(Wp_hi + off);
            bf16x8 bl = *(const bf16x8*)(Wp_lo + off);
            acc = __builtin_amdgcn_mfma_f32_16x16x32_bf16(a[c], bh, acc, 0, 0, 0);
            acc = __builtin_amdgcn_mfma_f32_16x16x32_bf16(a[c], bl, acc, 0, 0, 0);
        }
        int colx = t * 16 + m;
#pragma unroll
        for (int r = 0; r < 4; r++) {
            int orow = row0 + q * 4 + r;
            if (orow < n) Cbf[(size_t)orow * N + colx] = (__bf16)(acc[r] * dscale[r]);
        }
    }
}

// ---------------- aggregation: pure gather-sum; rows are k x 16 slots ----------------
__global__ __launch_bounds__(256) void k_agg128(const unsigned int* __restrict__ t32,
                                                const int* __restrict__ rowptr,
                                                const int* __restrict__ col,
                                                const float* __restrict__ dinv,
                                                const float* __restrict__ bias,
                                                unsigned int* __restrict__ out, int n) {
    int w = (int)((blockIdx.x * 256u + threadIdx.x) >> 6);
    int lane = threadIdx.x & 63;
    if (w >= n) return;
    unsigned us = t32[(size_t)w * 64 + lane];
    float a0 = bflo(us);
    float a1 = bfhi(us);
    int p = rowptr[w], pe = rowptr[w + 1];
    for (; p < pe; p += 16) {  // row length is a multiple of 16: all gathers in flight
        int4 c0 = *(const int4*)(col + p);
        int4 c1 = *(const int4*)(col + p + 4);
        int4 c2 = *(const int4*)(col + p + 8);
        int4 c3 = *(const int4*)(col + p + 12);
        unsigned u0 = t32[((size_t)c0.x << 6) + lane];
        unsigned u1 = t32[((size_t)c0.y << 6) + lane];
        unsigned u2 = t32[((size_t)c0.z << 6) + lane];
        unsigned u3 = t32[((size_t)c0.w << 6) + lane];
        unsigned u4 = t32[((size_t)c1.x << 6) + lane];
        unsigned u5 = t32[((size_t)c1.y << 6) + lane];
        unsigned u6 = t32[((size_t)c1.z << 6) + lane];
        unsigned u7 = t32[((size_t)c1.w << 6) + lane];
        unsigned u8 = t32[((size_t)c2.x << 6) + lane];
        unsigned u9 = t32[((size_t)c2.y << 6) + lane];
        unsigned ua = t32[((size_t)c2.z << 6) + lane];
        unsigned ub = t32[((size_t)c2.w << 6) + lane];
        unsigned uc = t32[((size_t)c3.x << 6) + lane];
        unsigned ud = t32[((size_t)c3.y << 6) + lane];
        unsigned ue = t32[((size_t)c3.z << 6) + lane];
        unsigned uf = t32[((size_t)c3.w << 6) + lane];
        a0 += bflo(u0); a1 += bfhi(u0);
        a0 += bflo(u1); a1 += bfhi(u1);
        a0 += bflo(u2); a1 += bfhi(u2);
        a0 += bflo(u3); a1 += bfhi(u3);
        a0 += bflo(u4); a1 += bfhi(u4);
        a0 += bflo(u5); a1 += bfhi(u5);
        a0 += bflo(u6); a1 += bfhi(u6);
        a0 += bflo(u7); a1 += bfhi(u7);
        a0 += bflo(u8); a1 += bfhi(u8);
        a0 += bflo(u9); a1 += bfhi(u9);
        a0 += bflo(ua); a1 += bfhi(ua);
        a0 += bflo(ub); a1 += bfhi(ub);
        a0 += bflo(uc); a1 += bfhi(uc);
        a0 += bflo(ud); a1 += bfhi(ud);
        a0 += bflo(ue); a1 += bfhi(ue);
        a0 += bflo(uf); a1 += bfhi(uf);
    }
    float di = dinv[w];
    BF2 o;
    o.h[0] = (__bf16)fmaxf(di * a0 + bias[lane * 2], 0.f);
    o.h[1] = (__bf16)fmaxf(di * a1 + bias[lane * 2 + 1], 0.f);
    out[(size_t)w * 64 + lane] = o.u;
}

__global__ __launch_bounds__(256) void k_agg64(const unsigned short* __restrict__ t16,
                                               const int* __restrict__ rowptr,
                                               const int* __restrict__ col,
                                               const float* __restrict__ dinv,
                                               const float* __restrict__ bias,
                                               __bf16* __restrict__ out, int n) {
    int w = (int)((blockIdx.x * 256u + threadIdx.x) >> 6);
    int lane = threadIdx.x & 63;
    if (w >= n) return;
    float acc = __uint_as_float((unsigned)t16[(size_t)w * 64 + lane] << 16);
    int p = rowptr[w], pe = rowptr[w + 1];
    for (; p < pe; p += 16) {
        int4 c0 = *(const int4*)(col + p);
        int4 c1 = *(const int4*)(col + p + 4);
        int4 c2 = *(const int4*)(col + p + 8);
        int4 c3 = *(const int4*)(col + p + 12);
        unsigned u0 = t16[((size_t)c0.x << 6) + lane];
        unsigned u1 = t16[((size_t)c0.y << 6) + lane];
        unsigned u2 = t16[((size_t)c0.z << 6) + lane];
        unsigned u3 = t16[((size_t)c0.w << 6) + lane];
        unsigned u4 = t16[((size_t)c1.x << 6) + lane];
        unsigned u5 = t16[((size_t)c1.y << 6) + lane];
        unsigned u6 = t16[((size_t)c1.z << 6) + lane];
        unsigned u7 = t16[((size_t)c1.w << 6) + lane];
        unsigned u8 = t16[((size_t)c2.x << 6) + lane];
        unsigned u9 = t16[((size_t)c2.y << 6) + lane];
        unsigned ua = t16[((size_t)c2.z << 6) + lane];
        unsigned ub = t16[((size_t)c2.w << 6) + lane];
        unsigned uc = t16[((size_t)c3.x << 6) + lane];
        unsigned ud = t16[((size_t)c3.y << 6) + lane];
        unsigned ue = t16[((size_t)c3.z << 6) + lane];
        unsigned uf = t16[((size_t)c3.w << 6) + lane];
        acc += __uint_as_float(u0 << 16);
        acc += __uint_as_float(u1 << 16);
        acc += __uint_as_float(u2 << 16);
        acc += __uint_as_float(u3 << 16);
        acc += __uint_as_float(u4 << 16);
        acc += __uint_as_float(u5 << 16);
        acc += __uint_as_float(u6 << 16);
        acc += __uint_as_float(u7 << 16);
        acc += __uint_as_float(u8 << 16);
        acc += __uint_as_float(u9 << 16);
        acc += __uint_as_float(ua << 16);
        acc += __uint_as_float(ub << 16);
        acc += __uint_as_float(uc << 16);
        acc += __uint_as_float(ud << 16);
        acc += __uint_as_float(ue << 16);
        acc += __uint_as_float(uf << 16);
    }
    out[(size_t)w * 64 + lane] = (__bf16)fmaxf(dinv[w] * acc + bias[lane], 0.f);
}

// ---------------- fused mean-pool + MLP head ----------------
__global__ __launch_bounds__(256) void k_poolmlp(const unsigned short* __restrict__ h,
                                                 const int* __restrict__ gstart,
                                                 const float* __restrict__ demo,
                                                 const float* __restrict__ Wf1,
                                                 const float* __restrict__ bf1,
                                                 const float* __restrict__ Wf2,
                                                 const float* __restrict__ bf2,
                                                 const float* __restrict__ Wf3,
                                                 const float* __restrict__ bf3,
                                                 float* __restrict__ out, int G) {
    int g = blockIdx.x;
    int tid = threadIdx.x;
    int lane = tid & 63;
    int wv = tid >> 6;
    int s = gstart[g], e = gstart[g + 1];
    float acc = 0.f;
    for (int i = s + wv; i < e; i += 4)
        acc += __uint_as_float((unsigned)h[(size_t)i * 64 + lane] << 16);
    __shared__ float red[4][64];
    __shared__ float zin[72];
    __shared__ float z1[64];
    __shared__ float z2[32];
    red[wv][lane] = acc;
    if (tid >= 64 && tid < 72) zin[tid] = demo[g * 8 + (tid - 64)];
    __syncthreads();
    if (tid < 64) {
        float v = red[0][tid] + red[1][tid] + red[2][tid] + red[3][tid];
        zin[tid] = v / fmaxf((float)(e - s), 1.0f);
    }
    __syncthreads();
    if (tid < 64) {
        float a = bf1[tid];
        for (int k = 0; k < 72; k++) a += zin[k] * Wf1[k * 64 + tid];
        z1[tid] = fmaxf(a, 0.f);
    }
    __syncthreads();
    if (tid < 32) {
        float a2 = bf2[tid];
        for (int k = 0; k < 64; k++) a2 += z1[k] * Wf2[k * 32 + tid];
        z2[tid] = fmaxf(a2, 0.f);
    }
    __syncthreads();
    if (tid < 2) {
        float a3 = bf3[tid];
        for (int k = 0; k < 32; k++) a3 += z2[k] * Wf3[k * 2 + tid];
        out[g * 2 + tid] = a3;
    }
}

extern "C" void kernel_launch(void* const* d_in, const int* in_sizes, int n_in,
                              void* d_out, int out_size, void* d_ws, size_t ws_size,
                              hipStream_t stream) {
    const float* x    = (const float*)d_in[0];
    const int*   ei   = (const int*)d_in[1];
    const int*   batch= (const int*)d_in[2];
    const float* demo = (const float*)d_in[3];
    const float* W1   = (const float*)d_in[4];
    const float* b1   = (const float*)d_in[5];
    const float* W2   = (const float*)d_in[6];
    const float* b2   = (const float*)d_in[7];
    const float* W3   = (const float*)d_in[8];
    const float* b3   = (const float*)d_in[9];
    const float* Wf1  = (const float*)d_in[10];
    const float* bf1  = (const float*)d_in[11];
    const float* Wf2  = (const float*)d_in[12];
    const float* bf2  = (const float*)d_in[13];
    const float* Wf3  = (const float*)d_in[14];
    const float* bf3  = (const float*)d_in[15];
    float* out = (float*)d_out;

    const int n = in_sizes[0] / 128;  // 50000
    const int E = in_sizes[1] / 2;    // 600000
    const int G = in_sizes[3] / 8;    // 100
    const int Epad = E + 15 * n;      // worst-case padded CSR size (pad to 16)
    const int nchunks = (n + 4095) / 4096;

    char* ws = (char*)d_ws;
    auto alloc = [&](size_t bytes) {
        char* p = ws;
        ws += (bytes + 255) & ~(size_t)255;
        return p;
    };
    int*    cnt    = (int*)alloc((size_t)n * 4);
    float*  dinv   = (float*)alloc((size_t)n * 4);
    int*    rowptr = (int*)alloc((size_t)(n + 1) * 4);
    int*    fill2  = (int*)alloc((size_t)n * 4);
    int*    partial= (int*)alloc((size_t)nchunks * 4);
    int*    col    = (int*)alloc((size_t)Epad * 4);
    __bf16* tbf    = (__bf16*)alloc((size_t)(n + 1) * 128 * 2);  // ts (layers 1/2), row n = 0
    __bf16* hbuf   = (__bf16*)alloc((size_t)n * 128 * 2);        // agg out bf16
    __bf16* t3bf   = (__bf16*)alloc((size_t)(n + 1) * 64 * 2);   // ts layer 3, row n = 0
    __bf16* h3     = (__bf16*)alloc((size_t)n * 64 * 2);         // agg3 out (bf16)
    __bf16* Wp1h   = (__bf16*)alloc(128 * 128 * 2);
    __bf16* Wp1l   = (__bf16*)alloc(128 * 128 * 2);
    __bf16* Wp2h   = (__bf16*)alloc(128 * 128 * 2);
    __bf16* Wp2l   = (__bf16*)alloc(128 * 128 * 2);
    __bf16* Wp3h   = (__bf16*)alloc(128 * 64 * 2);
    __bf16* Wp3l   = (__bf16*)alloc(128 * 64 * 2);
    int*    gstart = (int*)alloc((size_t)(G + 1) * 4);

    const int* srcv = ei;
    const int* dstv = ei + E;

    hipMemsetAsync(cnt, 0, (size_t)n * 4, stream);

    const int EB = (E + 255) / 256;
    // k_pre: EB degree blocks + 1 gstart block + 20 wpack blocks (W1,W2,W3)
    k_pre<<<EB + 21, 256, 0, stream>>>(dstv, cnt, batch, gstart, W1, Wp1h, Wp1l,
                                       W2, W3, Wp2h, Wp2l, Wp3h, Wp3l, E, n, G, EB);
    // parallel scan: partial sums -> per-chunk scan + writes
    k_sum<<<nchunks, 1024, 0, stream>>>(cnt, partial, dinv,
                                        (unsigned int*)tbf, (unsigned int*)t3bf, n);
    k_out<<<nchunks, 1024, 0, stream>>>(cnt, partial, rowptr, fill2, col, n, nchunks);
    k_csr<<<EB, 256, 0, stream>>>(srcv, dstv, fill2, col, E);

    int waves = (n + 15) / 16;
    int gemm_blocks = (waves + 3) / 4;
    int agg_blocks = (int)(((size_t)n * 64 + 255) / 256);

    // Layer 1: ts = dinv (.) (x@W1); h = relu(dinv*(gather-sum) + b1)
    k_gemm_f32<8><<<gemm_blocks, 256, 0, stream>>>(x, Wp1h, Wp1l, dinv, tbf, n);
    k_agg128<<<agg_blocks, 256, 0, stream>>>((const unsigned int*)tbf, rowptr, col,
                                             dinv, b1, (unsigned int*)hbuf, n);
    // Layer 2
    k_gemm_bf16<8><<<gemm_blocks, 256, 0, stream>>>(hbuf, Wp2h, Wp2l, dinv, tbf, n);
    k_agg128<<<agg_blocks, 256, 0, stream>>>((const unsigned int*)tbf, rowptr, col,
                                             dinv, b2, (unsigned int*)hbuf, n);
    // Layer 3 (128 -> 64)
    k_gemm_bf16<4><<<gemm_blocks, 256, 0, stream>>>(hbuf, Wp3h, Wp3l, dinv, t3bf, n);
    k_agg64<<<agg_blocks, 256, 0, stream>>>((const unsigned short*)t3bf, rowptr, col,
                                            dinv, b3, h3, n);

    k_poolmlp<<<G, 256, 0, stream>>>((const unsigned short*)h3, gstart, demo,
                                     Wf1, bf1, Wf2, bf2, Wf3, bf3, out, G);
}